// Round 3
// baseline (127.282 us; speedup 1.0000x reference)
//
#include <hip/hip_runtime.h>

typedef unsigned short u16;
typedef unsigned int u32;
typedef __attribute__((ext_vector_type(4))) float f32x4;
typedef __attribute__((ext_vector_type(8))) __bf16 bf16x8;
typedef __attribute__((ext_vector_type(4))) u16 u16x4;
typedef __attribute__((ext_vector_type(4))) float f32x4v;

#define LSEQ 128
#define KW 8
#define NP 2104
#define MTOT 33664   // BATCH*NP
#define FDIM 1088    // PAIR_FEAT
#define GPAD 1152    // 9*128

// ---- workspace layout (bytes) ----
#define WS_W1P  0ul          // u16 [1152*1088] = 2,506,752 B
#define WS_EMOB 2506752ul    // u16 [16*128*512] = 2,097,152 B
#define WS_CAUB 4603904ul    // u16 [16*128*512]
#define WS_SB   6701056ul    // u16 [17*1152] = 39,168 B (bf16, pad cols zero)
#define WS_W2P  6740224ul    // f32 [1152] (pad zero)
#define WS_TOFF 6744832ul    // int [128]  (end 6,745,344)

__device__ __forceinline__ u16 f2bf(float x) {
  union { float f; u32 u; } v; v.f = x;
  u32 r = v.u + 0x7fffu + ((v.u >> 16) & 1u);
  return (u16)(r >> 16);
}

__device__ __forceinline__ float bf2f(u16 x) {
  union { u32 u; float f; } v; v.u = ((u32)x) << 16; return v.f;
}

__device__ __forceinline__ void load_lds16(const void* g, void* l) {
  __builtin_amdgcn_global_load_lds(
      (const __attribute__((address_space(1))) void*)g,
      (__attribute__((address_space(3))) void*)l, 16, 0, 0);
}

// ---- fused setup ----
// blockIdx.x: [0,1224)     -> W1 -> bf16 padded [1152][1088]
//             [1224,3272)  -> emo/cau -> bf16
//             3272         -> tab_off + out_pos + W2p (padded)
//             [3273,3350)  -> Sb[r][g] (bf16, 1152-wide, pad zero)
//             [3350,3383)  -> pred = b2 init
__global__ __launch_bounds__(256)
void setup_all(const float* __restrict__ emo, const float* __restrict__ cau,
               const float* __restrict__ pos_emb, const float* __restrict__ W1,
               const float* __restrict__ b1, const float* __restrict__ W2,
               const float* __restrict__ b2,
               u16* __restrict__ W1p, u16* __restrict__ emoB,
               u16* __restrict__ cauB, u16* __restrict__ Sb,
               float* __restrict__ W2p, int* __restrict__ tab_off,
               float* __restrict__ pred, float* __restrict__ out_pos) {
  __shared__ float smL[17 * 64];
  const int bx = blockIdx.x;
  const int t = threadIdx.x;
  if (bx < 1224) {
    int idx = bx * 256 + t;
    if (idx >= 313344) return;
    int g = idx / 272;
    int f = (idx - g * 272) * 4;
    u16x4 o;
    if (g < 1088) {
      f32x4v v = *(const f32x4v*)&W1[g * 1088 + f];
      o.x = f2bf(v.x); o.y = f2bf(v.y); o.z = f2bf(v.z); o.w = f2bf(v.w);
    } else {
      o.x = 0; o.y = 0; o.z = 0; o.w = 0;
    }
    *(u16x4*)&W1p[(size_t)g * 1088 + f] = o;
  } else if (bx < 3272) {
    int idx = (bx - 1224) * 256 + t;
    if (idx < 262144) {
      f32x4v v = *(const f32x4v*)&emo[idx * 4];
      u16x4 o; o.x = f2bf(v.x); o.y = f2bf(v.y); o.z = f2bf(v.z); o.w = f2bf(v.w);
      *(u16x4*)&emoB[idx * 4] = o;
    } else {
      int k = idx - 262144;
      f32x4v v = *(const f32x4v*)&cau[k * 4];
      u16x4 o; o.x = f2bf(v.x); o.y = f2bf(v.y); o.z = f2bf(v.z); o.w = f2bf(v.w);
      *(u16x4*)&cauB[k * 4] = o;
    }
  } else if (bx == 3272) {
    if (t < LSEQ) {
      int i = t;
      int off = 0;
      for (int tt = 0; tt < i; ++tt) {
        int lo = tt - KW; if (lo < 0) lo = 0;
        int hi = tt + KW; if (hi > LSEQ - 1) hi = LSEQ - 1;
        off += hi - lo + 1;
      }
      tab_off[i] = off;
      int jlo = i - KW; if (jlo < 0) jlo = 0;
      int jhi = i + KW; if (jhi > LSEQ - 1) jhi = LSEQ - 1;
      for (int j = jlo; j <= jhi; ++j) {
        int p = off + (j - jlo);
        out_pos[2 * p]     = (float)(i + 1);
        out_pos[2 * p + 1] = (float)(j + 1);
      }
    }
    for (int g = t; g < GPAD; g += 256)
      W2p[g] = (g < FDIM) ? W2[g] : 0.f;
  } else if (bx < 3350) {
    // Sb blocks: recompute smoothed17 (f32) in LDS, then Sb slice -> bf16, 1152-wide
    for (int idx = t; idx < 17 * 64; idx += 256) {
      int r = idx >> 6, d = idx & 63;
      float acc = 0.f;
      for (int s = 0; s < 17; ++s) {
        float diff = (float)(r - s);
        int a = s - 8; if (a < 0) a = -a;
        float cnt = (float)(128 - a);
        acc += cnt * expf(-diff * diff) * pos_emb[s * 64 + d];
      }
      smL[idx] = acc;
    }
    __syncthreads();
    int idx2 = (bx - 3273) * 256 + t;
    if (idx2 < 17 * GPAD) {
      int r = idx2 / GPAD;
      int g = idx2 - r * GPAD;
      u16 ov = 0;
      if (g < FDIM) {
        float a = b1[g];
        const float* wr = &W1[(size_t)g * 1088 + 1024];
        const float* sr = &smL[r * 64];
#pragma unroll 8
        for (int d = 0; d < 64; ++d) a = fmaf(sr[d], wr[d], a);
        ov = f2bf(a);
      }
      Sb[idx2] = ov;
    }
  } else {
    int k = (bx - 3350) * 256 + t;
    if (k < 8416) {
      float bv = b2[0];
      f32x4v o = {bv, bv, bv, bv};
      *(f32x4v*)&pred[k * 4] = o;
    }
  }
}

// ---- fused GEMM + combine ----
// block = (mblk 0..63: 32 i-rows of batch b) x (gt 0..8: 128 g-cols)
// E[32][128] = emo rows x W1p[:, 0:512); C[48][128] = cau halo rows x W1p[:, 512:1024)
// then pred[q] += sum_{g in tile} W2[g]*relu(E[i]+C[j]+S[r]) for the window pairs
__global__ __launch_bounds__(256, 2)
void fused_pair(const u16* __restrict__ emoB, const u16* __restrict__ cauB,
                const u16* __restrict__ W1p, const u16* __restrict__ Sb,
                const float* __restrict__ W2p, const int* __restrict__ tab_off,
                float* __restrict__ pred) {
  __shared__ __align__(16) u16 As[48 * 32];
  __shared__ __align__(16) u16 Bs[128 * 32];
  __shared__ __align__(16) float Et[32 * 132];   // pad stride 132
  __shared__ __align__(16) float Ct[48 * 132];
  __shared__ u16 Sl[17 * 136];                   // pad stride 136
  __shared__ int toff[32];

  const int tid = threadIdx.x;
  const int id = blockIdx.x;                     // 576 = 8*72
  const int sid = (id & 7) * 72 + (id >> 3);     // XCD-chunked, bijective
  const int mblk = sid / 9;
  const int gt = sid - mblk * 9;
  const int b = mblk >> 2;
  const int lo = (mblk & 3) * 32;
  const int cb = lo - 8;                         // C halo base (may be <0)
  const int gbase = gt * 128;

  const int lane = tid & 63;
  const int w = tid >> 6;
  const int lrow = lane & 15;
  const int lk = (lane >> 4) * 8;
  const int wmE = (w >> 1) * 16;
  const int wnE = (w & 1) * 64;

  // stage S slice (reg path, padded stride) + toff
  for (int u = tid; u < 272; u += 256) {
    const int r = u >> 4, cu = u & 15;
    const u16* src = &Sb[r * GPAD + gbase + cu * 8];
    u16x4 v0 = *(const u16x4*)src;
    u16x4 v1 = *(const u16x4*)(src + 4);
    *(u16x4*)&Sl[r * 136 + cu * 8] = v0;
    *(u16x4*)&Sl[r * 136 + cu * 8 + 4] = v1;
  }
  if (tid < 32) toff[tid] = tab_off[lo + tid];

  const int srow = tid >> 2;
  const int ssub = (tid & 3) * 8;
  const u16* aE = emoB + ((size_t)(b * LSEQ + lo) << 9);
  const u16* bW = W1p + (size_t)gbase * FDIM;

  // ---- E GEMM (K = 0..512) ----
  f32x4 accE[4];
#pragma unroll
  for (int x = 0; x < 4; ++x) accE[x] = (f32x4){0.f, 0.f, 0.f, 0.f};
  for (int ks = 0; ks < 16; ++ks) {
    const int kofs = ks * 32;
    if (tid < 128) load_lds16(aE + srow * 512 + kofs + ssub, (char*)&As[0] + tid * 16);
    load_lds16(bW + srow * FDIM + kofs + ssub, (char*)&Bs[0] + tid * 16);
    load_lds16(bW + (srow + 64) * FDIM + kofs + ssub, (char*)&Bs[0] + tid * 16 + 4096);
    __syncthreads();
    bf16x8 av = *(const bf16x8*)&As[(wmE + lrow) * 32 + lk];
#pragma unroll
    for (int ni = 0; ni < 4; ++ni) {
      bf16x8 bvv = *(const bf16x8*)&Bs[(wnE + ni * 16 + lrow) * 32 + lk];
      accE[ni] = __builtin_amdgcn_mfma_f32_16x16x32_bf16(av, bvv, accE[ni], 0, 0, 0);
    }
    __syncthreads();
  }
  {
    const int mr = wmE + (lane >> 4) * 4;
#pragma unroll
    for (int ni = 0; ni < 4; ++ni) {
      const int n = wnE + ni * 16 + lrow;
#pragma unroll
      for (int r2 = 0; r2 < 4; ++r2)
        Et[(mr + r2) * 132 + n] = accE[ni][r2];
    }
  }

  // ---- C GEMM (K = 512..1024), 48 halo rows ----
  f32x4 accC[6];
#pragma unroll
  for (int x = 0; x < 6; ++x) accC[x] = (f32x4){0.f, 0.f, 0.f, 0.f};
  const int f0 = w * 6;
  const int rfL = f0 >> 3;
  const int rfH = (f0 + 5) >> 3;
  int csr = cb + srow;
  csr = (csr < 0) ? 0 : (csr > 127 ? 127 : csr);   // clamp OOB halo source
  const u16* aC = cauB + ((size_t)(b * LSEQ) << 9);
  for (int ks = 0; ks < 16; ++ks) {
    const int kofs = ks * 32;
    if (tid < 192) load_lds16(aC + csr * 512 + kofs + ssub, (char*)&As[0] + tid * 16);
    load_lds16(bW + srow * FDIM + 512 + kofs + ssub, (char*)&Bs[0] + tid * 16);
    load_lds16(bW + (srow + 64) * FDIM + 512 + kofs + ssub, (char*)&Bs[0] + tid * 16 + 4096);
    __syncthreads();
    bf16x8 avL = *(const bf16x8*)&As[(rfL * 16 + lrow) * 32 + lk];
    bf16x8 avH = *(const bf16x8*)&As[(rfH * 16 + lrow) * 32 + lk];
#pragma unroll
    for (int t = 0; t < 6; ++t) {
      const int f = f0 + t;
      bf16x8 av = ((f >> 3) == rfL) ? avL : avH;
      bf16x8 bvv = *(const bf16x8*)&Bs[((f & 7) * 16 + lrow) * 32 + lk];
      accC[t] = __builtin_amdgcn_mfma_f32_16x16x32_bf16(av, bvv, accC[t], 0, 0, 0);
    }
    __syncthreads();
  }
  {
#pragma unroll
    for (int t = 0; t < 6; ++t) {
      const int f = f0 + t;
      const int m = (f >> 3) * 16 + (lane >> 4) * 4;
      const int n = (f & 7) * 16 + lrow;
#pragma unroll
      for (int r2 = 0; r2 < 4; ++r2)
        Ct[(m + r2) * 132 + n] = accC[t][r2];
    }
  }
  __syncthreads();

  // ---- combine: 16-lane group per pair, 4 pairs/wave concurrent ----
  const int lg = lane >> 4;
  const int li = lane & 15;
  const float* w2g = W2p + gbase + li * 8;
  const f32x4v w2a = *(const f32x4v*)w2g;
  const f32x4v w2b = *(const f32x4v*)(w2g + 4);
  const int ib0 = w * 8;
  for (int ii = 0; ii < 8; ++ii) {
    const int il = ib0 + ii;
    const int i = lo + il;
    const f32x4v e0 = *(const f32x4v*)&Et[il * 132 + li * 8];
    const f32x4v e1 = *(const f32x4v*)&Et[il * 132 + li * 8 + 4];
    const int jlo_i = (i >= KW) ? (i - KW) : 0;
    const int qb = b * NP + toff[il] - jlo_i;    // q = qb + j
#pragma unroll
    for (int jt = 0; jt < 5; ++jt) {
      const int j = (jt < 4) ? (i - KW + jt * 4 + lg) : (i + KW);
      const int crow = (j - cb) * 132;           // always in [0,48*132)
      const f32x4v c0 = *(const f32x4v*)&Ct[crow + li * 8];
      const f32x4v c1 = *(const f32x4v*)&Ct[crow + li * 8 + 4];
      const int r = j - i + KW;
      const u16* sp = &Sl[r * 136 + li * 8];
      const u16x4 s0 = *(const u16x4*)sp;
      const u16x4 s1 = *(const u16x4*)(sp + 4);
      float a = fmaxf(e0.x + c0.x + bf2f(s0.x), 0.f) * w2a.x;
      a = fmaf(fmaxf(e0.y + c0.y + bf2f(s0.y), 0.f), w2a.y, a);
      a = fmaf(fmaxf(e0.z + c0.z + bf2f(s0.z), 0.f), w2a.z, a);
      a = fmaf(fmaxf(e0.w + c0.w + bf2f(s0.w), 0.f), w2a.w, a);
      a = fmaf(fmaxf(e1.x + c1.x + bf2f(s1.x), 0.f), w2b.x, a);
      a = fmaf(fmaxf(e1.y + c1.y + bf2f(s1.y), 0.f), w2b.y, a);
      a = fmaf(fmaxf(e1.z + c1.z + bf2f(s1.z), 0.f), w2b.z, a);
      a = fmaf(fmaxf(e1.w + c1.w + bf2f(s1.w), 0.f), w2b.w, a);
      a += __shfl_xor(a, 1, 16);
      a += __shfl_xor(a, 2, 16);
      a += __shfl_xor(a, 4, 16);
      a += __shfl_xor(a, 8, 16);
      const bool valid = (j >= 0) && (j <= 127) && (jt < 4 || lg == 0);
      if (li == 0 && valid) atomicAdd(&pred[qb + j], a);
    }
  }
}

extern "C" void kernel_launch(void* const* d_in, const int* in_sizes, int n_in,
                              void* d_out, int out_size, void* d_ws, size_t ws_size,
                              hipStream_t stream) {
  const float* h_emo = (const float*)d_in[0];
  const float* h_cau = (const float*)d_in[1];
  const float* pos_emb = (const float*)d_in[2];
  const float* W1 = (const float*)d_in[3];
  const float* b1 = (const float*)d_in[4];
  const float* W2 = (const float*)d_in[5];
  const float* b2 = (const float*)d_in[6];

  char* ws = (char*)d_ws;
  u16* W1p = (u16*)(ws + WS_W1P);
  u16* emoB = (u16*)(ws + WS_EMOB);
  u16* cauB = (u16*)(ws + WS_CAUB);
  u16* Sb = (u16*)(ws + WS_SB);
  float* W2p = (float*)(ws + WS_W2P);
  int* tab_off = (int*)(ws + WS_TOFF);

  float* pred = (float*)d_out;
  float* out_pos = (float*)d_out + MTOT;

  setup_all<<<3383, 256, 0, stream>>>(h_emo, h_cau, pos_emb, W1, b1, W2, b2,
                                      W1p, emoB, cauB, Sb, W2p, tab_off,
                                      pred, out_pos);
  fused_pair<<<576, 256, 0, stream>>>(emoB, cauB, W1p, Sb, W2p, tab_off, pred);
}

// Round 4
// 122.746 us; speedup vs baseline: 1.0370x; 1.0370x over previous
//
#include <hip/hip_runtime.h>

typedef unsigned short u16;
typedef unsigned int u32;
typedef __attribute__((ext_vector_type(4))) float f32x4;
typedef __attribute__((ext_vector_type(8))) __bf16 bf16x8;
typedef __attribute__((ext_vector_type(4))) u16 u16x4;
typedef __attribute__((ext_vector_type(4))) float f32x4v;

#define LSEQ 128
#define KW 8
#define NP 2104
#define MTOT 33664   // BATCH*NP
#define FDIM 1088    // PAIR_FEAT
#define GPAD 1152    // 9*128

// ---- workspace layout (bytes) ----
#define WS_W1P  0ul          // u16 [1152*1088] = 2,506,752 B
#define WS_EMOB 2506752ul    // u16 [16*128*512] = 2,097,152 B
#define WS_CAUB 4603904ul    // u16 [16*128*512]
#define WS_SB   6701056ul    // u16 [17*1088] = 36,992 B (bf16)
#define WS_TOFF 6738048ul    // int [128]
#define WS_EC   6738560ul    // f32 [4096*1152] = 18,874,368 B (end 25,612,928)

__device__ __forceinline__ u16 f2bf(float x) {
  union { float f; u32 u; } v; v.f = x;
  u32 r = v.u + 0x7fffu + ((v.u >> 16) & 1u);
  return (u16)(r >> 16);
}

__device__ __forceinline__ float bf2f(u16 x) {
  union { u32 u; float f; } v; v.u = ((u32)x) << 16; return v.f;
}

__device__ __forceinline__ void load_lds16(const void* g, void* l) {
  __builtin_amdgcn_global_load_lds(
      (const __attribute__((address_space(1))) void*)g,
      (__attribute__((address_space(3))) void*)l, 16, 0, 0);
}

// ---- fused setup (R2-proven) ----
// blockIdx.x: [0,1224)     -> W1 -> bf16 padded [1152][1088]
//             [1224,3272)  -> emo/cau -> bf16
//             3272         -> tab_off + out_pos
//             [3273,3346)  -> Sb[r][g] = bf16(b1[g] + sum_d sm17[r][d]*W1[g][1024+d])
__global__ __launch_bounds__(256)
void setup_all(const float* __restrict__ emo, const float* __restrict__ cau,
               const float* __restrict__ pos_emb, const float* __restrict__ W1,
               const float* __restrict__ b1,
               u16* __restrict__ W1p, u16* __restrict__ emoB,
               u16* __restrict__ cauB, u16* __restrict__ Sb,
               int* __restrict__ tab_off, float* __restrict__ out_pos) {
  __shared__ float smL[17 * 64];
  const int bx = blockIdx.x;
  const int t = threadIdx.x;
  if (bx < 1224) {
    int idx = bx * 256 + t;
    if (idx >= 313344) return;
    int g = idx / 272;
    int f = (idx - g * 272) * 4;
    u16x4 o;
    if (g < 1088) {
      f32x4v v = *(const f32x4v*)&W1[g * 1088 + f];
      o.x = f2bf(v.x); o.y = f2bf(v.y); o.z = f2bf(v.z); o.w = f2bf(v.w);
    } else {
      o.x = 0; o.y = 0; o.z = 0; o.w = 0;
    }
    *(u16x4*)&W1p[(size_t)g * 1088 + f] = o;
  } else if (bx < 3272) {
    int idx = (bx - 1224) * 256 + t;
    if (idx < 262144) {
      f32x4v v = *(const f32x4v*)&emo[idx * 4];
      u16x4 o; o.x = f2bf(v.x); o.y = f2bf(v.y); o.z = f2bf(v.z); o.w = f2bf(v.w);
      *(u16x4*)&emoB[idx * 4] = o;
    } else {
      int k = idx - 262144;
      f32x4v v = *(const f32x4v*)&cau[k * 4];
      u16x4 o; o.x = f2bf(v.x); o.y = f2bf(v.y); o.z = f2bf(v.z); o.w = f2bf(v.w);
      *(u16x4*)&cauB[k * 4] = o;
    }
  } else if (bx == 3272) {
    if (t < LSEQ) {
      int i = t;
      int off = 0;
      for (int tt = 0; tt < i; ++tt) {
        int lo = tt - KW; if (lo < 0) lo = 0;
        int hi = tt + KW; if (hi > LSEQ - 1) hi = LSEQ - 1;
        off += hi - lo + 1;
      }
      tab_off[i] = off;
      int jlo = i - KW; if (jlo < 0) jlo = 0;
      int jhi = i + KW; if (jhi > LSEQ - 1) jhi = LSEQ - 1;
      for (int j = jlo; j <= jhi; ++j) {
        int p = off + (j - jlo);
        out_pos[2 * p]     = (float)(i + 1);
        out_pos[2 * p + 1] = (float)(j + 1);
      }
    }
  } else {
    // Sb blocks: recompute smoothed17 (f32) in LDS, then Sb slice -> bf16
    for (int idx = t; idx < 17 * 64; idx += 256) {
      int r = idx >> 6, d = idx & 63;
      float acc = 0.f;
      for (int s = 0; s < 17; ++s) {
        float diff = (float)(r - s);
        int a = s - 8; if (a < 0) a = -a;
        float cnt = (float)(128 - a);
        acc += cnt * expf(-diff * diff) * pos_emb[s * 64 + d];
      }
      smL[idx] = acc;
    }
    __syncthreads();
    int idx2 = (bx - 3273) * 256 + t;
    if (idx2 < 17 * 1088) {
      int r = idx2 / 1088;
      int g = idx2 - r * 1088;
      float a = b1[g];
      const float* wr = &W1[(size_t)g * 1088 + 1024];
      const float* sr = &smL[r * 64];
#pragma unroll 8
      for (int d = 0; d < 64; ++d) a = fmaf(sr[d], wr[d], a);
      Sb[r * 1088 + g] = f2bf(a);
    }
  }
}

// ---- feature GEMM, barrier-free: fragments direct from L2 to registers ----
// EC[m][g] = sum_k A[m][k] * W1p[g][fsel+k], K=512.
// rows 0..2047: emo vs cols [0,512); rows 2048..4095: cau vs cols [512,1024).
// One wave per 64x64 tile; 1152 single-wave blocks; no LDS, no barriers.
__global__ __launch_bounds__(64, 2)
void feat_gemm(const u16* __restrict__ emoB, const u16* __restrict__ cauB,
               const u16* __restrict__ W1p, float* __restrict__ EC) {
  const int bid = blockIdx.x;                   // 1152 = 8*144
  const int sid = (bid & 7) * 144 + (bid >> 3); // XCD-chunked, bijective
  const int mt = sid / 18;
  const int nt = sid - mt * 18;
  const int m0 = mt * 64;
  const int n0 = nt * 64;

  const int lane = threadIdx.x;
  const int lrow = lane & 15;
  const int lk8 = (lane >> 4) * 8;

  const u16* asrc = (m0 < 2048) ? (emoB + (size_t)m0 * 512)
                                : (cauB + (size_t)(m0 - 2048) * 512);
  const int fofs = (m0 < 2048) ? 0 : 512;
  const u16* a0 = asrc + lrow * 512 + lk8;
  const u16* b0 = W1p + (size_t)(n0 + lrow) * FDIM + fofs + lk8;

  f32x4 acc[4][4];
#pragma unroll
  for (int mi = 0; mi < 4; ++mi)
#pragma unroll
    for (int ni = 0; ni < 4; ++ni) acc[mi][ni] = (f32x4){0.f, 0.f, 0.f, 0.f};

#pragma unroll 2
  for (int kk = 0; kk < 512; kk += 32) {
    bf16x8 av[4], bv[4];
#pragma unroll
    for (int x = 0; x < 4; ++x) {
      av[x] = *(const bf16x8*)(a0 + (size_t)(x * 16) * 512 + kk);
      bv[x] = *(const bf16x8*)(b0 + (size_t)(x * 16) * FDIM + kk);
    }
#pragma unroll
    for (int mi = 0; mi < 4; ++mi)
#pragma unroll
      for (int ni = 0; ni < 4; ++ni)
        acc[mi][ni] = __builtin_amdgcn_mfma_f32_16x16x32_bf16(av[mi], bv[ni], acc[mi][ni], 0, 0, 0);
  }

  const int r4 = (lane >> 4) * 4;
#pragma unroll
  for (int mi = 0; mi < 4; ++mi) {
#pragma unroll
    for (int ni = 0; ni < 4; ++ni) {
      float* dst = EC + (size_t)(m0 + mi * 16 + r4) * GPAD + n0 + ni * 16 + lrow;
#pragma unroll
      for (int r2 = 0; r2 < 4; ++r2) dst[(size_t)r2 * GPAD] = acc[mi][ni][r2];
    }
  }
}

// ---- combine (R2-proven): wave per (b,i)-row g-half; E,W2 in regs; S in LDS ----
// pred[q] = b2 + sum_g W2[g]*relu(E[b,i,g]+C[b,j,g]+S[r,g])
__global__ __launch_bounds__(256, 4)
void combine(const float* __restrict__ EC, const u16* __restrict__ Sb,
             const float* __restrict__ W2, const float* __restrict__ b2,
             const int* __restrict__ tab_off, float* __restrict__ pred) {
  __shared__ __align__(16) u16 Sl[17 * 1088];   // 36,992 B
  __shared__ float partA[2][17], partB[2][17];

  const int tid = threadIdx.x;
  const int bid = blockIdx.x;                   // 1024 = 8*128
  const int sb = (bid & 7) * 128 + (bid >> 3);  // XCD-chunked, bijective

  // stage S -> LDS (linear dest = base + tid*16)
  {
    char* dst = (char*)&Sl[0];
    const char* src = (const char*)Sb;
#pragma unroll
    for (int it = 0; it < 9; ++it)
      load_lds16(src + it * 4096 + tid * 16, dst + it * 4096 + tid * 16);
    if (tid < 8)
      load_lds16(src + 36864 + tid * 16, dst + 36864 + tid * 16);
  }

  const int w = tid >> 6;
  const int lane = tid & 63;
  const int h = w >> 1;       // which (b,i) of this block
  const int gh = w & 1;       // which g-half
  const int u = sb * 2 + h;
  const int b = u >> 7;
  const int i = u & 127;
  int jlo = i - KW; if (jlo < 0) jlo = 0;
  int jhi = i + KW; if (jhi > 127) jhi = 127;

  const float bias2 = b2[0];
  const float* Erow = EC + (size_t)(b * 128 + i) * GPAD;
  const float* Cbase = EC + (size_t)(2048 + b * 128) * GPAD;

  // per-lane g slice: gh0 -> [0,512), gh1 -> [512,1024) + tail 1024+lane
  const int g0 = gh * 512 + lane * 4;
  const int g1 = g0 + 256;
  const f32x4v e0 = *(const f32x4v*)(Erow + g0);
  const f32x4v e1 = *(const f32x4v*)(Erow + g1);
  const f32x4v w20 = *(const f32x4v*)(W2 + g0);
  const f32x4v w21 = *(const f32x4v*)(W2 + g1);
  float eT = 0.f, w2T = 0.f;
  if (gh) { eT = Erow[1024 + lane]; w2T = W2[1024 + lane]; }

  __syncthreads();  // S staged (barrier drains vmcnt)

  const float* Crow = Cbase + (size_t)jlo * GPAD;
  f32x4v c0 = *(const f32x4v*)(Crow + g0);
  f32x4v c1 = *(const f32x4v*)(Crow + g1);
  float cT = gh ? Crow[1024 + lane] : 0.f;

  for (int j = jlo; j <= jhi; ++j) {
    f32x4v n0 = c0, n1 = c1; float nT = cT;
    if (j < jhi) {
      const float* Nrow = Cbase + (size_t)(j + 1) * GPAD;
      n0 = *(const f32x4v*)(Nrow + g0);
      n1 = *(const f32x4v*)(Nrow + g1);
      if (gh) nT = Nrow[1024 + lane];
    }
    const int r = j - i + KW;
    const u16* srow = &Sl[r * 1088];
    u16x4 sa = *(const u16x4*)(srow + g0);
    u16x4 sc = *(const u16x4*)(srow + g1);

    float a = 0.f;
    a = fmaf(fmaxf(e0.x + c0.x + bf2f(sa.x), 0.f), w20.x, a);
    a = fmaf(fmaxf(e0.y + c0.y + bf2f(sa.y), 0.f), w20.y, a);
    a = fmaf(fmaxf(e0.z + c0.z + bf2f(sa.z), 0.f), w20.z, a);
    a = fmaf(fmaxf(e0.w + c0.w + bf2f(sa.w), 0.f), w20.w, a);
    a = fmaf(fmaxf(e1.x + c1.x + bf2f(sc.x), 0.f), w21.x, a);
    a = fmaf(fmaxf(e1.y + c1.y + bf2f(sc.y), 0.f), w21.y, a);
    a = fmaf(fmaxf(e1.z + c1.z + bf2f(sc.z), 0.f), w21.z, a);
    a = fmaf(fmaxf(e1.w + c1.w + bf2f(sc.w), 0.f), w21.w, a);
    if (gh) {
      float sT = bf2f(srow[1024 + lane]);
      a = fmaf(fmaxf(eT + cT + sT, 0.f), w2T, a);
    }

    a += __shfl_xor(a, 1);
    a += __shfl_xor(a, 2);
    a += __shfl_xor(a, 4);
    a += __shfl_xor(a, 8);
    a += __shfl_xor(a, 16);
    a += __shfl_xor(a, 32);
    if (lane == 0) {
      if (gh) partB[h][j - jlo] = a;
      else    partA[h][j - jlo] = a;
    }
    c0 = n0; c1 = n1; cT = nT;
  }
  __syncthreads();

  // finalize: wave 0 -> h=0, wave 1 -> h=1
  if (w < 2) {
    const int u2 = sb * 2 + w;
    const int bb = u2 >> 7;
    const int i2 = u2 & 127;
    int jl2 = i2 - KW; if (jl2 < 0) jl2 = 0;
    int jh2 = i2 + KW; if (jh2 > 127) jh2 = 127;
    const int cnt2 = jh2 - jl2 + 1;
    if (lane < cnt2) {
      const int q = bb * NP + tab_off[i2] + lane;
      pred[q] = partA[w][lane] + partB[w][lane] + bias2;
    }
  }
}

extern "C" void kernel_launch(void* const* d_in, const int* in_sizes, int n_in,
                              void* d_out, int out_size, void* d_ws, size_t ws_size,
                              hipStream_t stream) {
  const float* h_emo = (const float*)d_in[0];
  const float* h_cau = (const float*)d_in[1];
  const float* pos_emb = (const float*)d_in[2];
  const float* W1 = (const float*)d_in[3];
  const float* b1 = (const float*)d_in[4];
  const float* W2 = (const float*)d_in[5];
  const float* b2 = (const float*)d_in[6];

  char* ws = (char*)d_ws;
  u16* W1p = (u16*)(ws + WS_W1P);
  u16* emoB = (u16*)(ws + WS_EMOB);
  u16* cauB = (u16*)(ws + WS_CAUB);
  u16* Sb = (u16*)(ws + WS_SB);
  int* tab_off = (int*)(ws + WS_TOFF);
  float* EC = (float*)(ws + WS_EC);

  float* pred = (float*)d_out;
  float* out_pos = (float*)d_out + MTOT;

  setup_all<<<3346, 256, 0, stream>>>(h_emo, h_cau, pos_emb, W1, b1,
                                      W1p, emoB, cauB, Sb, tab_off, out_pos);
  feat_gemm<<<1152, 64, 0, stream>>>(emoB, cauB, W1p, EC);
  combine<<<1024, 256, 0, stream>>>(EC, Sb, W2, b2, tab_off, pred);
}

// Round 5
// 110.258 us; speedup vs baseline: 1.1544x; 1.1133x over previous
//
#include <hip/hip_runtime.h>

typedef unsigned short u16;
typedef unsigned int u32;
typedef __attribute__((ext_vector_type(4))) float f32x4;
typedef __attribute__((ext_vector_type(8))) __bf16 bf16x8;
typedef __attribute__((ext_vector_type(4))) u16 u16x4;
typedef __attribute__((ext_vector_type(8))) u16 u16x8;
typedef __attribute__((ext_vector_type(4))) float f32x4v;

#define LSEQ 128
#define KW 8
#define NP 2104
#define MTOT 33664   // BATCH*NP
#define FDIM 1088    // PAIR_FEAT
#define GPAD 1152    // 9*128

// ---- workspace layout (bytes) ----
#define WS_W1P  0ul          // u16 [1152*1088] = 2,506,752 B
#define WS_EMOB 2506752ul    // u16 [16*128*512] = 2,097,152 B
#define WS_CAUB 4603904ul    // u16 [16*128*512]
#define WS_SB   6701056ul    // u16 [17*1088] = 36,992 B (bf16)
#define WS_TOFF 6738048ul    // int [128]
#define WS_EC   6738560ul    // f32 [4096*1152] = 18,874,368 B (end 25,612,928)

__device__ __forceinline__ u16 f2bf(float x) {
  union { float f; u32 u; } v; v.f = x;
  u32 r = v.u + 0x7fffu + ((v.u >> 16) & 1u);
  return (u16)(r >> 16);
}

__device__ __forceinline__ float bf2f(u16 x) {
  union { u32 u; float f; } v; v.u = ((u32)x) << 16; return v.f;
}

__device__ __forceinline__ void load_lds16(const void* g, void* l) {
  __builtin_amdgcn_global_load_lds(
      (const __attribute__((address_space(1))) void*)g,
      (__attribute__((address_space(3))) void*)l, 16, 0, 0);
}

// ---- fused setup (R2-proven, 8-floats/thread) ----
// blockIdx.x: [0,612)      -> W1 -> bf16 padded [1152][1088]
//             [612,1636)   -> emo/cau -> bf16
//             1636         -> tab_off + out_pos
//             [1637,1710)  -> Sb[r][g] = bf16(b1[g] + sum_d sm17[r][d]*W1[g][1024+d])
__global__ __launch_bounds__(256)
void setup_all(const float* __restrict__ emo, const float* __restrict__ cau,
               const float* __restrict__ pos_emb, const float* __restrict__ W1,
               const float* __restrict__ b1,
               u16* __restrict__ W1p, u16* __restrict__ emoB,
               u16* __restrict__ cauB, u16* __restrict__ Sb,
               int* __restrict__ tab_off, float* __restrict__ out_pos) {
  __shared__ float smL[17 * 64];
  const int bx = blockIdx.x;
  const int t = threadIdx.x;
  if (bx < 612) {
    int idx = bx * 256 + t;              // 156,672 units of 8 u16, exact
    int g = idx / 136;
    int f = (idx - g * 136) * 8;
    u16x8 o;
    if (g < 1088) {
      f32x4v v0 = *(const f32x4v*)&W1[g * 1088 + f];
      f32x4v v1 = *(const f32x4v*)&W1[g * 1088 + f + 4];
      o[0] = f2bf(v0.x); o[1] = f2bf(v0.y); o[2] = f2bf(v0.z); o[3] = f2bf(v0.w);
      o[4] = f2bf(v1.x); o[5] = f2bf(v1.y); o[6] = f2bf(v1.z); o[7] = f2bf(v1.w);
    } else {
      o = (u16x8)0;
    }
    *(u16x8*)&W1p[(size_t)g * 1088 + f] = o;
  } else if (bx < 1636) {
    int idx = (bx - 612) * 256 + t;      // 262,144 units of 8 floats, exact
    const float* src;
    u16* dst;
    if (idx < 131072) { src = emo + idx * 8; dst = emoB + idx * 8; }
    else { int k = idx - 131072; src = cau + k * 8; dst = cauB + k * 8; }
    f32x4v v0 = *(const f32x4v*)src;
    f32x4v v1 = *(const f32x4v*)(src + 4);
    u16x8 o;
    o[0] = f2bf(v0.x); o[1] = f2bf(v0.y); o[2] = f2bf(v0.z); o[3] = f2bf(v0.w);
    o[4] = f2bf(v1.x); o[5] = f2bf(v1.y); o[6] = f2bf(v1.z); o[7] = f2bf(v1.w);
    *(u16x8*)dst = o;
  } else if (bx == 1636) {
    if (t < LSEQ) {
      int i = t;
      int off = 0;
      for (int tt = 0; tt < i; ++tt) {
        int lo = tt - KW; if (lo < 0) lo = 0;
        int hi = tt + KW; if (hi > LSEQ - 1) hi = LSEQ - 1;
        off += hi - lo + 1;
      }
      tab_off[i] = off;
      int jlo = i - KW; if (jlo < 0) jlo = 0;
      int jhi = i + KW; if (jhi > LSEQ - 1) jhi = LSEQ - 1;
      for (int j = jlo; j <= jhi; ++j) {
        int p = off + (j - jlo);
        out_pos[2 * p]     = (float)(i + 1);
        out_pos[2 * p + 1] = (float)(j + 1);
      }
    }
  } else {
    // Sb blocks: recompute smoothed17 (f32) in LDS, then Sb slice -> bf16
    for (int idx = t; idx < 17 * 64; idx += 256) {
      int r = idx >> 6, d = idx & 63;
      float acc = 0.f;
      for (int s = 0; s < 17; ++s) {
        float diff = (float)(r - s);
        int a = s - 8; if (a < 0) a = -a;
        float cnt = (float)(128 - a);
        acc += cnt * expf(-diff * diff) * pos_emb[s * 64 + d];
      }
      smL[idx] = acc;
    }
    __syncthreads();
    int idx2 = (bx - 1637) * 256 + t;
    if (idx2 < 17 * 1088) {
      int r = idx2 / 1088;
      int g = idx2 - r * 1088;
      float a = b1[g];
      const float* wr = &W1[(size_t)g * 1088 + 1024];
      const float* sr = &smL[r * 64];
#pragma unroll 8
      for (int d = 0; d < 64; ++d) a = fmaf(sr[d], wr[d], a);
      Sb[r * 1088 + g] = f2bf(a);
    }
  }
}

// ---- feature GEMM: 2-phase counted pipeline (T3-min), double-buffered LDS ----
// EC[m][g] = sum_k A[m][k] * W1p[g][fsel+k], K=512. BM=64, BN=128, grid (64,9).
// One s_barrier per K-step; staging loads fly under ds_read+MFMA of prev step.
__global__ __launch_bounds__(256, 4)
void feat_gemm(const u16* __restrict__ emoB, const u16* __restrict__ cauB,
               const u16* __restrict__ W1p, float* __restrict__ EC) {
  __shared__ __align__(16) u16 As2[2][64 * 32];    // 2 x 4 KB
  __shared__ __align__(16) u16 Bs2[2][128 * 32];   // 2 x 8 KB

  const int tid = threadIdx.x;
  const int mblk = blockIdx.x;          // 0..63
  const int gbase = blockIdx.y * 128;   // 0..1024

  const int lane = tid & 63;
  const int w = tid >> 6;
  const int lrow = lane & 15;
  const int lk = (lane >> 4) * 8;
  const int wm = (w >> 1) * 32;
  const int wn = (w & 1) * 64;

  const int row0 = tid >> 2;            // 0..63
  const int sub = (tid & 3) * 8;

  const u16* Asrc = (mblk < 32) ? emoB : cauB;
  const int arow = (mblk & 31) * 64;
  const int fsel = (mblk < 32) ? 0 : 512;

  const u16* aP = Asrc + (size_t)(arow + row0) * 512 + sub;
  const u16* bP = W1p + (size_t)(gbase + row0) * FDIM + fsel + sub;
  const u16* bQ = bP + 64u * FDIM;

#define FSTAGE(ks, bb)                                                     \
  do {                                                                     \
    const int _f = (ks) * 32;                                              \
    load_lds16(aP + _f, (char*)&As2[bb][0] + tid * 16);                    \
    load_lds16(bP + _f, (char*)&Bs2[bb][0] + tid * 16);                    \
    load_lds16(bQ + _f, (char*)&Bs2[bb][0] + 4096 + tid * 16);             \
  } while (0)

  f32x4 acc[2][4];
#pragma unroll
  for (int mi = 0; mi < 2; ++mi)
#pragma unroll
    for (int ni = 0; ni < 4; ++ni) acc[mi][ni] = (f32x4){0.f, 0.f, 0.f, 0.f};

  // prologue
  FSTAGE(0, 0);
  asm volatile("s_waitcnt vmcnt(0)");
  __builtin_amdgcn_s_barrier();
  __builtin_amdgcn_sched_barrier(0);

  int cur = 0;
#pragma unroll 2
  for (int ks = 0; ks < 16; ++ks) {
    if (ks < 15) FSTAGE(ks + 1, cur ^ 1);   // prefetch next into idle buffer

    bf16x8 av[2], bv[4];
#pragma unroll
    for (int mi = 0; mi < 2; ++mi)
      av[mi] = *(const bf16x8*)&As2[cur][(wm + mi * 16 + lrow) * 32 + lk];
#pragma unroll
    for (int ni = 0; ni < 4; ++ni)
      bv[ni] = *(const bf16x8*)&Bs2[cur][(wn + ni * 16 + lrow) * 32 + lk];
#pragma unroll
    for (int mi = 0; mi < 2; ++mi)
#pragma unroll
      for (int ni = 0; ni < 4; ++ni)
        acc[mi][ni] = __builtin_amdgcn_mfma_f32_16x16x32_bf16(av[mi], bv[ni], acc[mi][ni], 0, 0, 0);

    // drain this iter's staging loads (they overlapped ds_read+MFMA), then sync
    asm volatile("s_waitcnt vmcnt(0)");
    __builtin_amdgcn_s_barrier();
    __builtin_amdgcn_sched_barrier(0);
    cur ^= 1;
  }
#undef FSTAGE

  const int rbase = mblk * 64 + wm + ((lane >> 4) << 2);
#pragma unroll
  for (int mi = 0; mi < 2; ++mi) {
#pragma unroll
    for (int ni = 0; ni < 4; ++ni) {
      const int ocol = gbase + wn + ni * 16 + lrow;
      float* dst = EC + (size_t)(rbase + mi * 16) * GPAD + ocol;
#pragma unroll
      for (int r2 = 0; r2 < 4; ++r2) dst[(size_t)r2 * GPAD] = acc[mi][ni][r2];
    }
  }
}

// ---- combine (R2-proven, unchanged): wave per (b,i)-row g-half ----
// pred[q] = b2 + sum_g W2[g]*relu(E[b,i,g]+C[b,j,g]+S[r,g])
__global__ __launch_bounds__(256, 4)
void combine(const float* __restrict__ EC, const u16* __restrict__ Sb,
             const float* __restrict__ W2, const float* __restrict__ b2,
             const int* __restrict__ tab_off, float* __restrict__ pred) {
  __shared__ __align__(16) u16 Sl[17 * 1088];   // 36,992 B
  __shared__ float partA[2][17], partB[2][17];

  const int tid = threadIdx.x;
  const int bid = blockIdx.x;                   // 1024 = 8*128
  const int sb = (bid & 7) * 128 + (bid >> 3);  // XCD-chunked, bijective

  // stage S -> LDS (linear dest = base + tid*16)
  {
    char* dst = (char*)&Sl[0];
    const char* src = (const char*)Sb;
#pragma unroll
    for (int it = 0; it < 9; ++it)
      load_lds16(src + it * 4096 + tid * 16, dst + it * 4096 + tid * 16);
    if (tid < 8)
      load_lds16(src + 36864 + tid * 16, dst + 36864 + tid * 16);
  }

  const int w = tid >> 6;
  const int lane = tid & 63;
  const int h = w >> 1;       // which (b,i) of this block
  const int gh = w & 1;       // which g-half
  const int u = sb * 2 + h;
  const int b = u >> 7;
  const int i = u & 127;
  int jlo = i - KW; if (jlo < 0) jlo = 0;
  int jhi = i + KW; if (jhi > 127) jhi = 127;

  const float bias2 = b2[0];
  const float* Erow = EC + (size_t)(b * 128 + i) * GPAD;
  const float* Cbase = EC + (size_t)(2048 + b * 128) * GPAD;

  // per-lane g slice: gh0 -> [0,512), gh1 -> [512,1024) + tail 1024+lane
  const int g0 = gh * 512 + lane * 4;
  const int g1 = g0 + 256;
  const f32x4v e0 = *(const f32x4v*)(Erow + g0);
  const f32x4v e1 = *(const f32x4v*)(Erow + g1);
  const f32x4v w20 = *(const f32x4v*)(W2 + g0);
  const f32x4v w21 = *(const f32x4v*)(W2 + g1);
  float eT = 0.f, w2T = 0.f;
  if (gh) { eT = Erow[1024 + lane]; w2T = W2[1024 + lane]; }

  __syncthreads();  // S staged (barrier drains vmcnt)

  const float* Crow = Cbase + (size_t)jlo * GPAD;
  f32x4v c0 = *(const f32x4v*)(Crow + g0);
  f32x4v c1 = *(const f32x4v*)(Crow + g1);
  float cT = gh ? Crow[1024 + lane] : 0.f;

  for (int j = jlo; j <= jhi; ++j) {
    f32x4v n0 = c0, n1 = c1; float nT = cT;
    if (j < jhi) {
      const float* Nrow = Cbase + (size_t)(j + 1) * GPAD;
      n0 = *(const f32x4v*)(Nrow + g0);
      n1 = *(const f32x4v*)(Nrow + g1);
      if (gh) nT = Nrow[1024 + lane];
    }
    const int r = j - i + KW;
    const u16* srow = &Sl[r * 1088];
    u16x4 sa = *(const u16x4*)(srow + g0);
    u16x4 sc = *(const u16x4*)(srow + g1);

    float a = 0.f;
    a = fmaf(fmaxf(e0.x + c0.x + bf2f(sa.x), 0.f), w20.x, a);
    a = fmaf(fmaxf(e0.y + c0.y + bf2f(sa.y), 0.f), w20.y, a);
    a = fmaf(fmaxf(e0.z + c0.z + bf2f(sa.z), 0.f), w20.z, a);
    a = fmaf(fmaxf(e0.w + c0.w + bf2f(sa.w), 0.f), w20.w, a);
    a = fmaf(fmaxf(e1.x + c1.x + bf2f(sc.x), 0.f), w21.x, a);
    a = fmaf(fmaxf(e1.y + c1.y + bf2f(sc.y), 0.f), w21.y, a);
    a = fmaf(fmaxf(e1.z + c1.z + bf2f(sc.z), 0.f), w21.z, a);
    a = fmaf(fmaxf(e1.w + c1.w + bf2f(sc.w), 0.f), w21.w, a);
    if (gh) {
      float sT = bf2f(srow[1024 + lane]);
      a = fmaf(fmaxf(eT + cT + sT, 0.f), w2T, a);
    }

    a += __shfl_xor(a, 1);
    a += __shfl_xor(a, 2);
    a += __shfl_xor(a, 4);
    a += __shfl_xor(a, 8);
    a += __shfl_xor(a, 16);
    a += __shfl_xor(a, 32);
    if (lane == 0) {
      if (gh) partB[h][j - jlo] = a;
      else    partA[h][j - jlo] = a;
    }
    c0 = n0; c1 = n1; cT = nT;
  }
  __syncthreads();

  // finalize: wave 0 -> h=0, wave 1 -> h=1
  if (w < 2) {
    const int u2 = sb * 2 + w;
    const int bb = u2 >> 7;
    const int i2 = u2 & 127;
    int jl2 = i2 - KW; if (jl2 < 0) jl2 = 0;
    int jh2 = i2 + KW; if (jh2 > 127) jh2 = 127;
    const int cnt2 = jh2 - jl2 + 1;
    if (lane < cnt2) {
      const int q = bb * NP + tab_off[i2] + lane;
      pred[q] = partA[w][lane] + partB[w][lane] + bias2;
    }
  }
}

extern "C" void kernel_launch(void* const* d_in, const int* in_sizes, int n_in,
                              void* d_out, int out_size, void* d_ws, size_t ws_size,
                              hipStream_t stream) {
  const float* h_emo = (const float*)d_in[0];
  const float* h_cau = (const float*)d_in[1];
  const float* pos_emb = (const float*)d_in[2];
  const float* W1 = (const float*)d_in[3];
  const float* b1 = (const float*)d_in[4];
  const float* W2 = (const float*)d_in[5];
  const float* b2 = (const float*)d_in[6];

  char* ws = (char*)d_ws;
  u16* W1p = (u16*)(ws + WS_W1P);
  u16* emoB = (u16*)(ws + WS_EMOB);
  u16* cauB = (u16*)(ws + WS_CAUB);
  u16* Sb = (u16*)(ws + WS_SB);
  int* tab_off = (int*)(ws + WS_TOFF);
  float* EC = (float*)(ws + WS_EC);

  float* pred = (float*)d_out;
  float* out_pos = (float*)d_out + MTOT;

  setup_all<<<1710, 256, 0, stream>>>(h_emo, h_cau, pos_emb, W1, b1,
                                      W1p, emoB, cauB, Sb, tab_off, out_pos);
  feat_gemm<<<dim3(64, 9), 256, 0, stream>>>(emoB, cauB, W1p, EC);
  combine<<<1024, 256, 0, stream>>>(EC, Sb, W2, b2, tab_off, pred);
}

// Round 6
// 108.687 us; speedup vs baseline: 1.1711x; 1.0145x over previous
//
#include <hip/hip_runtime.h>

typedef unsigned short u16;
typedef unsigned int u32;
typedef __attribute__((ext_vector_type(4))) float f32x4;
typedef __attribute__((ext_vector_type(8))) __bf16 bf16x8;
typedef __attribute__((ext_vector_type(4))) u16 u16x4;
typedef __attribute__((ext_vector_type(8))) u16 u16x8;
typedef __attribute__((ext_vector_type(4))) float f32x4v;

#define LSEQ 128
#define KW 8
#define NP 2104
#define MTOT 33664   // BATCH*NP
#define FDIM 1088    // PAIR_FEAT
#define GPAD 1152    // 9*128

// ---- workspace layout (bytes) ----
#define WS_W1P  0ul          // u16 [1152*1088] = 2,506,752 B
#define WS_EMOB 2506752ul    // u16 [16*128*512] = 2,097,152 B
#define WS_CAUB 4603904ul    // u16 [16*128*512]
#define WS_SB   6701056ul    // u16 [17*1088] = 36,992 B (bf16)
#define WS_TOFF 6738048ul    // int [128]
#define WS_EC   6738560ul    // f32 [4096*1152] = 18,874,368 B (end 25,612,928)

__device__ __forceinline__ u16 f2bf(float x) {
  union { float f; u32 u; } v; v.f = x;
  u32 r = v.u + 0x7fffu + ((v.u >> 16) & 1u);
  return (u16)(r >> 16);
}

__device__ __forceinline__ float bf2f(u16 x) {
  union { u32 u; float f; } v; v.u = ((u32)x) << 16; return v.f;
}

__device__ __forceinline__ void load_lds16(const void* g, void* l) {
  __builtin_amdgcn_global_load_lds(
      (const __attribute__((address_space(1))) void*)g,
      (__attribute__((address_space(3))) void*)l, 16, 0, 0);
}

// ---- kernel 1: conversions only (everything feat consumes) ----
// blockIdx.x: [0,612)    -> W1 -> bf16 padded [1152][1088]
//             [612,1636) -> emo/cau -> bf16
__global__ __launch_bounds__(256)
void convert_all(const float* __restrict__ emo, const float* __restrict__ cau,
                 const float* __restrict__ W1,
                 u16* __restrict__ W1p, u16* __restrict__ emoB,
                 u16* __restrict__ cauB) {
  const int bx = blockIdx.x;
  const int t = threadIdx.x;
  if (bx < 612) {
    int idx = bx * 256 + t;              // 156,672 units of 8 u16, exact
    int g = idx / 136;
    int f = (idx - g * 136) * 8;
    u16x8 o;
    if (g < 1088) {
      f32x4v v0 = *(const f32x4v*)&W1[g * 1088 + f];
      f32x4v v1 = *(const f32x4v*)&W1[g * 1088 + f + 4];
      o[0] = f2bf(v0.x); o[1] = f2bf(v0.y); o[2] = f2bf(v0.z); o[3] = f2bf(v0.w);
      o[4] = f2bf(v1.x); o[5] = f2bf(v1.y); o[6] = f2bf(v1.z); o[7] = f2bf(v1.w);
    } else {
      o = (u16x8)0;
    }
    *(u16x8*)&W1p[(size_t)g * 1088 + f] = o;
  } else {
    int idx = (bx - 612) * 256 + t;      // 262,144 units of 8 floats, exact
    const float* src;
    u16* dst;
    if (idx < 131072) { src = emo + idx * 8; dst = emoB + idx * 8; }
    else { int k = idx - 131072; src = cau + k * 8; dst = cauB + k * 8; }
    f32x4v v0 = *(const f32x4v*)src;
    f32x4v v1 = *(const f32x4v*)(src + 4);
    u16x8 o;
    o[0] = f2bf(v0.x); o[1] = f2bf(v0.y); o[2] = f2bf(v0.z); o[3] = f2bf(v0.w);
    o[4] = f2bf(v1.x); o[5] = f2bf(v1.y); o[6] = f2bf(v1.z); o[7] = f2bf(v1.w);
    *(u16x8*)dst = o;
  }
}

// ---- kernel 2: feature GEMM (blocks 0..575) + aux Sb/tab (blocks 576..649) ----
// feat: EC[m][g] = sum_k A[m][k]*W1p[g][fsel+k], K=512, BM=64 BN=128,
//       2-phase double-buffered LDS, one barrier per K-step.
// aux:  Sb[r][g] = bf16(b1[g] + sum_d sm17[r][d]*W1[g][1024+d]); tab_off/out_pos.
//       Aux depends only on raw inputs -> runs in feat's shadow.
__global__ __launch_bounds__(256, 4)
void feat_aux(const u16* __restrict__ emoB, const u16* __restrict__ cauB,
              const u16* __restrict__ W1p, float* __restrict__ EC,
              const float* __restrict__ pos_emb, const float* __restrict__ W1,
              const float* __restrict__ b1, u16* __restrict__ Sb,
              int* __restrict__ tab_off, float* __restrict__ out_pos) {
  __shared__ __align__(16) u16 As2[2][64 * 32];    // 2 x 4 KB
  __shared__ __align__(16) u16 Bs2[2][128 * 32];   // 2 x 8 KB (aliased by aux smL)

  const int bid = blockIdx.x;
  const int tid = threadIdx.x;

  if (bid >= 576) {
    const int bid2 = bid - 576;
    if (bid2 < 73) {
      // Sb: recompute smoothed17 (f32) in (aliased) LDS, then one 256-elem slice
      float* smL = (float*)&Bs2[0][0];             // 4352 B scratch
      for (int idx = tid; idx < 17 * 64; idx += 256) {
        int r = idx >> 6, d = idx & 63;
        float acc = 0.f;
        for (int s = 0; s < 17; ++s) {
          float diff = (float)(r - s);
          int a = s - 8; if (a < 0) a = -a;
          float cnt = (float)(128 - a);
          acc += cnt * expf(-diff * diff) * pos_emb[s * 64 + d];
        }
        smL[idx] = acc;
      }
      __syncthreads();
      int idx2 = bid2 * 256 + tid;
      if (idx2 < 17 * 1088) {
        int r = idx2 / 1088;
        int g = idx2 - r * 1088;
        float a = b1[g];
        const float* wr = &W1[(size_t)g * 1088 + 1024];
        const float* sr = &smL[r * 64];
#pragma unroll 8
        for (int d = 0; d < 64; ++d) a = fmaf(sr[d], wr[d], a);
        Sb[idx2] = f2bf(a);
      }
    } else {
      // tab block
      if (tid < LSEQ) {
        int i = tid;
        int off = 0;
        for (int tt = 0; tt < i; ++tt) {
          int lo = tt - KW; if (lo < 0) lo = 0;
          int hi = tt + KW; if (hi > LSEQ - 1) hi = LSEQ - 1;
          off += hi - lo + 1;
        }
        tab_off[i] = off;
        int jlo = i - KW; if (jlo < 0) jlo = 0;
        int jhi = i + KW; if (jhi > LSEQ - 1) jhi = LSEQ - 1;
        for (int j = jlo; j <= jhi; ++j) {
          int p = off + (j - jlo);
          out_pos[2 * p]     = (float)(i + 1);
          out_pos[2 * p + 1] = (float)(j + 1);
        }
      }
    }
    return;
  }

  // ---- feat path: bid = gt*64 + mblk (mblk fastest, matches dim3(64,9)) ----
  const int mblk = bid & 63;
  const int gbase = (bid >> 6) * 128;

  const int lane = tid & 63;
  const int w = tid >> 6;
  const int lrow = lane & 15;
  const int lk = (lane >> 4) * 8;
  const int wm = (w >> 1) * 32;
  const int wn = (w & 1) * 64;

  const int row0 = tid >> 2;            // 0..63
  const int sub = (tid & 3) * 8;

  const u16* Asrc = (mblk < 32) ? emoB : cauB;
  const int arow = (mblk & 31) * 64;
  const int fsel = (mblk < 32) ? 0 : 512;

  const u16* aP = Asrc + (size_t)(arow + row0) * 512 + sub;
  const u16* bP = W1p + (size_t)(gbase + row0) * FDIM + fsel + sub;
  const u16* bQ = bP + 64u * FDIM;

#define FSTAGE(ks, bb)                                                     \
  do {                                                                     \
    const int _f = (ks) * 32;                                              \
    load_lds16(aP + _f, (char*)&As2[bb][0] + tid * 16);                    \
    load_lds16(bP + _f, (char*)&Bs2[bb][0] + tid * 16);                    \
    load_lds16(bQ + _f, (char*)&Bs2[bb][0] + 4096 + tid * 16);             \
  } while (0)

  f32x4 acc[2][4];
#pragma unroll
  for (int mi = 0; mi < 2; ++mi)
#pragma unroll
    for (int ni = 0; ni < 4; ++ni) acc[mi][ni] = (f32x4){0.f, 0.f, 0.f, 0.f};

  FSTAGE(0, 0);
  asm volatile("s_waitcnt vmcnt(0)");
  __builtin_amdgcn_s_barrier();
  __builtin_amdgcn_sched_barrier(0);

  int cur = 0;
#pragma unroll 2
  for (int ks = 0; ks < 16; ++ks) {
    if (ks < 15) FSTAGE(ks + 1, cur ^ 1);   // prefetch next into idle buffer

    bf16x8 av[2], bv[4];
#pragma unroll
    for (int mi = 0; mi < 2; ++mi)
      av[mi] = *(const bf16x8*)&As2[cur][(wm + mi * 16 + lrow) * 32 + lk];
#pragma unroll
    for (int ni = 0; ni < 4; ++ni)
      bv[ni] = *(const bf16x8*)&Bs2[cur][(wn + ni * 16 + lrow) * 32 + lk];
#pragma unroll
    for (int mi = 0; mi < 2; ++mi)
#pragma unroll
      for (int ni = 0; ni < 4; ++ni)
        acc[mi][ni] = __builtin_amdgcn_mfma_f32_16x16x32_bf16(av[mi], bv[ni], acc[mi][ni], 0, 0, 0);

    asm volatile("s_waitcnt vmcnt(0)");
    __builtin_amdgcn_s_barrier();
    __builtin_amdgcn_sched_barrier(0);
    cur ^= 1;
  }
#undef FSTAGE

  const int rbase = mblk * 64 + wm + ((lane >> 4) << 2);
#pragma unroll
  for (int mi = 0; mi < 2; ++mi) {
#pragma unroll
    for (int ni = 0; ni < 4; ++ni) {
      const int ocol = gbase + wn + ni * 16 + lrow;
      float* dst = EC + (size_t)(rbase + mi * 16) * GPAD + ocol;
#pragma unroll
      for (int r2 = 0; r2 < 4; ++r2) dst[(size_t)r2 * GPAD] = acc[mi][ni][r2];
    }
  }
}

// ---- combine: wave per (b,i)-row g-half; E,W2 in regs; S direct from L2 ----
// pred[q] = b2 + sum_g W2[g]*relu(E[b,i,g]+C[b,j,g]+S[r,g])
__global__ __launch_bounds__(256, 4)
void combine(const float* __restrict__ EC, const u16* __restrict__ Sb,
             const float* __restrict__ W2, const float* __restrict__ b2,
             const int* __restrict__ tab_off, float* __restrict__ pred) {
  __shared__ float partA[2][17], partB[2][17];

  const int tid = threadIdx.x;
  const int bid = blockIdx.x;                   // 1024 = 8*128
  const int sb = (bid & 7) * 128 + (bid >> 3);  // XCD-chunked, bijective

  const int w = tid >> 6;
  const int lane = tid & 63;
  const int h = w >> 1;       // which (b,i) of this block
  const int gh = w & 1;       // which g-half
  const int u = sb * 2 + h;
  const int b = u >> 7;
  const int i = u & 127;
  int jlo = i - KW; if (jlo < 0) jlo = 0;
  int jhi = i + KW; if (jhi > 127) jhi = 127;

  const float bias2 = b2[0];
  const float* Erow = EC + (size_t)(b * 128 + i) * GPAD;
  const float* Cbase = EC + (size_t)(2048 + b * 128) * GPAD;

  // per-lane g slice: gh0 -> [0,512), gh1 -> [512,1024) + tail 1024+lane
  const int g0 = gh * 512 + lane * 4;
  const int g1 = g0 + 256;
  const f32x4v e0 = *(const f32x4v*)(Erow + g0);
  const f32x4v e1 = *(const f32x4v*)(Erow + g1);
  const f32x4v w20 = *(const f32x4v*)(W2 + g0);
  const f32x4v w21 = *(const f32x4v*)(W2 + g1);
  float eT = 0.f, w2T = 0.f;
  if (gh) { eT = Erow[1024 + lane]; w2T = W2[1024 + lane]; }

  const float* Crow = Cbase + (size_t)jlo * GPAD;
  f32x4v c0 = *(const f32x4v*)(Crow + g0);
  f32x4v c1 = *(const f32x4v*)(Crow + g1);
  float cT = gh ? Crow[1024 + lane] : 0.f;

  for (int j = jlo; j <= jhi; ++j) {
    f32x4v n0 = c0, n1 = c1; float nT = cT;
    if (j < jhi) {
      const float* Nrow = Cbase + (size_t)(j + 1) * GPAD;
      n0 = *(const f32x4v*)(Nrow + g0);
      n1 = *(const f32x4v*)(Nrow + g1);
      if (gh) nT = Nrow[1024 + lane];
    }
    const int r = j - i + KW;
    const u16* srow = Sb + r * 1088;
    u16x4 sa = *(const u16x4*)(srow + g0);
    u16x4 sc = *(const u16x4*)(srow + g1);

    float a = 0.f;
    a = fmaf(fmaxf(e0.x + c0.x + bf2f(sa.x), 0.f), w20.x, a);
    a = fmaf(fmaxf(e0.y + c0.y + bf2f(sa.y), 0.f), w20.y, a);
    a = fmaf(fmaxf(e0.z + c0.z + bf2f(sa.z), 0.f), w20.z, a);
    a = fmaf(fmaxf(e0.w + c0.w + bf2f(sa.w), 0.f), w20.w, a);
    a = fmaf(fmaxf(e1.x + c1.x + bf2f(sc.x), 0.f), w21.x, a);
    a = fmaf(fmaxf(e1.y + c1.y + bf2f(sc.y), 0.f), w21.y, a);
    a = fmaf(fmaxf(e1.z + c1.z + bf2f(sc.z), 0.f), w21.z, a);
    a = fmaf(fmaxf(e1.w + c1.w + bf2f(sc.w), 0.f), w21.w, a);
    if (gh) {
      float sT = bf2f(srow[1024 + lane]);
      a = fmaf(fmaxf(eT + cT + sT, 0.f), w2T, a);
    }

    a += __shfl_xor(a, 1);
    a += __shfl_xor(a, 2);
    a += __shfl_xor(a, 4);
    a += __shfl_xor(a, 8);
    a += __shfl_xor(a, 16);
    a += __shfl_xor(a, 32);
    if (lane == 0) {
      if (gh) partB[h][j - jlo] = a;
      else    partA[h][j - jlo] = a;
    }
    c0 = n0; c1 = n1; cT = nT;
  }
  __syncthreads();

  // finalize: wave 0 -> h=0, wave 1 -> h=1
  if (w < 2) {
    const int u2 = sb * 2 + w;
    const int bb = u2 >> 7;
    const int i2 = u2 & 127;
    int jl2 = i2 - KW; if (jl2 < 0) jl2 = 0;
    int jh2 = i2 + KW; if (jh2 > 127) jh2 = 127;
    const int cnt2 = jh2 - jl2 + 1;
    if (lane < cnt2) {
      const int q = bb * NP + tab_off[i2] + lane;
      pred[q] = partA[w][lane] + partB[w][lane] + bias2;
    }
  }
}

extern "C" void kernel_launch(void* const* d_in, const int* in_sizes, int n_in,
                              void* d_out, int out_size, void* d_ws, size_t ws_size,
                              hipStream_t stream) {
  const float* h_emo = (const float*)d_in[0];
  const float* h_cau = (const float*)d_in[1];
  const float* pos_emb = (const float*)d_in[2];
  const float* W1 = (const float*)d_in[3];
  const float* b1 = (const float*)d_in[4];
  const float* W2 = (const float*)d_in[5];
  const float* b2 = (const float*)d_in[6];

  char* ws = (char*)d_ws;
  u16* W1p = (u16*)(ws + WS_W1P);
  u16* emoB = (u16*)(ws + WS_EMOB);
  u16* cauB = (u16*)(ws + WS_CAUB);
  u16* Sb = (u16*)(ws + WS_SB);
  int* tab_off = (int*)(ws + WS_TOFF);
  float* EC = (float*)(ws + WS_EC);

  float* pred = (float*)d_out;
  float* out_pos = (float*)d_out + MTOT;

  convert_all<<<1636, 256, 0, stream>>>(h_emo, h_cau, W1, W1p, emoB, cauB);
  feat_aux<<<650, 256, 0, stream>>>(emoB, cauB, W1p, EC,
                                    pos_emb, W1, b1, Sb, tab_off, out_pos);
  combine<<<1024, 256, 0, stream>>>(EC, Sb, W2, b2, tab_off, pred);
}